// Round 8
// baseline (282.492 us; speedup 1.0000x reference)
//
#include <hip/hip_runtime.h>
#include <hip/hip_bf16.h>
#include <stdint.h>

#define B 8
#define N 4096
#define C 1024
#define H 16
#define D 64
// SCALE = D^-0.5 = 0.125 — folded into wbuf in wu_kernel (exact pow2:
// bf16(0.125*x) == 0.125*bf16(x), so logits are bit-identical).

static __device__ __forceinline__ float bf_lo(uint32_t u) {
    union { uint32_t i; float f; } c; c.i = u << 16; return c.f;
}
static __device__ __forceinline__ float bf_hi(uint32_t u) {
    union { uint32_t i; float f; } c; c.i = u & 0xffff0000u; return c.f;
}

// VALU-only wave64 sum: row_shr prefix + row_bcast combine; total in lane 63.
#define DPP_ADD(s, ctrl, rmask)                                              \
    s += __int_as_float(__builtin_amdgcn_update_dpp(                         \
        0, __float_as_int(s), ctrl, rmask, 0xf, true))

static __device__ __forceinline__ float wave_sum_dpp(float s) {
    DPP_ADD(s, 0x111, 0xf);  // row_shr:1
    DPP_ADD(s, 0x112, 0xf);  // row_shr:2
    DPP_ADD(s, 0x114, 0xf);  // row_shr:4
    DPP_ADD(s, 0x118, 0xf);  // row_shr:8  -> lane15 of each row = row sum
    DPP_ADD(s, 0x142, 0xa);  // row_bcast:15
    DPP_ADD(s, 0x143, 0xc);  // row_bcast:31
    return s;                // lane 63 holds the full 64-lane sum
}

// Kernel A: one wave per W row r (0..2C); computes k[b,*,r] (r<C) or v (r>=C)
// for ALL 8 batches -> W read exactly once. emb (32 KB) stays L2-hot.
__global__ __launch_bounds__(256, 2)
void kv_kernel(const float* __restrict__ emb,
               const float* __restrict__ Wk,
               const float* __restrict__ Wv,
               float* __restrict__ kbuf,
               float* __restrict__ vbuf) {
    int wave = (blockIdx.x * blockDim.x + threadIdx.x) >> 6;  // 0..2047
    int lane = threadIdx.x & 63;
    int r = wave;
    const float* Wrow = (r < C) ? (Wk + (size_t)r * C) : (Wv + (size_t)(r - C) * C);
    float4 w4[4];
#pragma unroll
    for (int j = 0; j < 4; ++j) w4[j] = *(const float4*)(Wrow + (lane + 64 * j) * 4);
    float acc[B];
#pragma unroll
    for (int b = 0; b < B; ++b) {
        const float* e = emb + (size_t)b * C;
        float a = 0.f;
#pragma unroll
        for (int j = 0; j < 4; ++j) {
            float4 e4 = *(const float4*)(e + (lane + 64 * j) * 4);
            a += w4[j].x * e4.x + w4[j].y * e4.y + w4[j].z * e4.z + w4[j].w * e4.w;
        }
        acc[b] = a;
    }
#pragma unroll
    for (int off = 32; off; off >>= 1)
#pragma unroll
        for (int b = 0; b < B; ++b) acc[b] += __shfl_xor(acc[b], off, 64);
    if (lane == 0) {
        float* dst = (r < C) ? (kbuf + r) : (vbuf + (r - C));
#pragma unroll
        for (int b = 0; b < B; ++b) dst[b * C] = acc[b];
    }
}

// Kernel B: fold weights, batch loop innermost (each Wq/Wp element read once).
// wbuf now pre-scaled by 0.125 (exact pow2; commutes with bf16 rounding).
__global__ __launch_bounds__(256)
void wu_kernel(const float* __restrict__ Wq,
               const float* __restrict__ Wp,
               const float* __restrict__ kbuf,
               const float* __restrict__ vbuf,
               __hip_bfloat16* __restrict__ wbuf,
               __hip_bfloat16* __restrict__ ubuf) {
    int id = blockIdx.x;
    int t = threadIdx.x;
    if (id < 64) {
        int h = id >> 2;
        int c = ((id & 3) << 8) + t;
        const float* kk = kbuf + h * D;  // k[b][hD+d] at kk[b*C + d]
        float acc[B];
#pragma unroll
        for (int b = 0; b < B; ++b) acc[b] = 0.f;
#pragma unroll 4
        for (int d = 0; d < D; ++d) {
            float wv = Wq[(size_t)(h * D + d) * C + c];
#pragma unroll
            for (int b = 0; b < B; ++b) acc[b] += kk[(size_t)b * C + d] * wv;
        }
#pragma unroll
        for (int b = 0; b < B; ++b)
            wbuf[(size_t)(b * H + h) * C + c] = __float2bfloat16(0.125f * acc[b]);
    } else {
        int id2 = id - 64;
        int h = id2 >> 2;
        int cp = ((id2 & 3) << 8) + t;
        const float* vv = vbuf + h * D;  // v[b][hD+d] at vv[b*C + d]
        float aq[4][B];
#pragma unroll
        for (int q = 0; q < 4; ++q)
#pragma unroll
            for (int b = 0; b < B; ++b) aq[q][b] = 0.f;
#pragma unroll
        for (int q = 0; q < 4; ++q) {
#pragma unroll
            for (int m = 0; m < 4; ++m) {
                int d0 = q * 16 + m * 4;
                float4 w4 = *(const float4*)(Wp + (size_t)cp * C + h * D + d0);
#pragma unroll
                for (int b = 0; b < B; ++b) {
                    const float* vb = vv + (size_t)b * C + d0;
                    aq[q][b] += w4.x * vb[0] + w4.y * vb[1]
                              + w4.z * vb[2] + w4.w * vb[3];
                }
            }
        }
#pragma unroll
        for (int b = 0; b < B; ++b)
            ubuf[(size_t)(b * H + h) * C + cp] =
                __float2bfloat16((aq[0][b] + aq[1][b]) + (aq[2][b] + aq[3][b]));
    }
}

// Kernel C: fused main pass — 8 WAVES/SIMD version.
// R7 post-mortem: no pipe saturated (VALU 52%, LDS ~45%, HBM 28%) at
// 4 waves/SIMD -> latency-limited by serial DPP/exp chains. Fix: double TLP.
//   - bf16-packed LDS (w_s+u_s = 64 KB + 2 KB sig) -> TWO 1024-thread
//     blocks per CU (132 KB <= 160) = 32 waves/CU = 8 waves/SIMD.
//   - VGPR must be <= 64 (blocks are atomic): 2-row groups (f[2][4]=32
//     live), bp4 reloaded per group (never live across phases), sigmoid
//     computed+stored from lane 63 (no broadcast shuffles),
//     __launch_bounds__(1024, 8).
//   - Grid (N/64, B) = 512 blocks = exactly 2/CU; 4 rows per wave as
//     2 groups of 2.
// Kept: rolled head loops (R3), two-phase f-reuse + DPP sum (R7),
// 0-conflict LDS patterns, scale pre-folded (bit-identical logits).
__global__ __launch_bounds__(1024, 8)
void main_kernel(const float* __restrict__ fea,
                 const __hip_bfloat16* __restrict__ wbuf,
                 const __hip_bfloat16* __restrict__ ubuf,
                 const float* __restrict__ bp,
                 float* __restrict__ out) {
    __shared__ uint32_t w_s[H * C / 2];   // bf16x2 packed, 32 KB (pre-scaled)
    __shared__ uint32_t u_s[H * C / 2];   // 32 KB
    __shared__ float sig_s[16 * H * 2];   // 2 KB: 16 waves x 16 heads x 2 rows
    const int b = blockIdx.y;
    const int tile = blockIdx.x;
    const int tid = threadIdx.x;

    {
        const uint4* wsrc = (const uint4*)(wbuf + (size_t)b * H * C);
        const uint4* usrc = (const uint4*)(ubuf + (size_t)b * H * C);
        uint4* wdst = (uint4*)w_s;
        uint4* udst = (uint4*)u_s;
#pragma unroll
        for (int i = 0; i < H * C / 8 / 1024; ++i) {  // 2 iters
            wdst[tid + i * 1024] = wsrc[tid + i * 1024];
            udst[tid + i * 1024] = usrc[tid + i * 1024];
        }
    }
    __syncthreads();

    const int lane = tid & 63;
    const int wv = tid >> 6;          // 0..15
    const int row0 = tile * 64 + wv * 4;
    float* sigp = sig_s + wv * (H * 2);

    const float* fbase = fea + ((size_t)b * N + row0) * C + 4 * lane;
    float* obase = out + ((size_t)b * N + row0) * C + 4 * lane;

#pragma unroll 1
    for (int g = 0; g < 2; ++g) {
        // ---- Phase 1: logits for 2 rows x 16 heads ----
        float4 f[2][4];
#pragma unroll
        for (int r = 0; r < 2; ++r)
#pragma unroll
            for (int j = 0; j < 4; ++j)
                f[r][j] = *(const float4*)(fbase + (size_t)(2 * g + r) * C + 256 * j);

#pragma unroll 1
        for (int h = 0; h < H; ++h) {
            const uint32_t* wrow = w_s + h * (C / 2) + 2 * lane;
            float sp[2][4];
#pragma unroll
            for (int j = 0; j < 4; ++j) {
                uint2 p = *(const uint2*)(wrow + 128 * j);
                float lx = bf_lo(p.x), hx = bf_hi(p.x);
                float ly = bf_lo(p.y), hy = bf_hi(p.y);
#pragma unroll
                for (int r = 0; r < 2; ++r)
                    sp[r][j] = f[r][j].x * lx + f[r][j].y * hx
                             + f[r][j].z * ly + f[r][j].w * hy;
            }
            float s0 = (sp[0][0] + sp[0][1]) + (sp[0][2] + sp[0][3]);
            float s1 = (sp[1][0] + sp[1][1]) + (sp[1][2] + sp[1][3]);
            s0 = wave_sum_dpp(s0);
            s1 = wave_sum_dpp(s1);
            // Only lane 63 has the full sums; sigmoid there and store.
            s0 = 1.f / (1.f + __expf(-s0));
            s1 = 1.f / (1.f + __expf(-s1));
            if (lane == 63) *(float2*)(sigp + h * 2) = make_float2(s0, s1);
        }

        // ---- Phase 2: f becomes acc; sweep u with broadcast sig ----
        {
            const float* bpp = bp + 4 * lane;
#pragma unroll
            for (int j = 0; j < 4; ++j) {
                float4 bp4 = *(const float4*)(bpp + 256 * j);
#pragma unroll
                for (int r = 0; r < 2; ++r) {
                    f[r][j].x += bp4.x; f[r][j].y += bp4.y;
                    f[r][j].z += bp4.z; f[r][j].w += bp4.w;
                }
            }
        }

#pragma unroll 1
        for (int h = 0; h < H; ++h) {
            float2 sg = *(const float2*)(sigp + h * 2);  // uniform broadcast
            const uint32_t* urow = u_s + h * (C / 2) + 2 * lane;
#pragma unroll
            for (int j = 0; j < 4; ++j) {
                uint2 p = *(const uint2*)(urow + 128 * j);
                float lx = bf_lo(p.x), hx = bf_hi(p.x);
                float ly = bf_lo(p.y), hy = bf_hi(p.y);
                f[0][j].x += sg.x * lx; f[0][j].y += sg.x * hx;
                f[0][j].z += sg.x * ly; f[0][j].w += sg.x * hy;
                f[1][j].x += sg.y * lx; f[1][j].y += sg.y * hx;
                f[1][j].z += sg.y * ly; f[1][j].w += sg.y * hy;
            }
        }

#pragma unroll
        for (int r = 0; r < 2; ++r)
#pragma unroll
            for (int j = 0; j < 4; ++j)
                *(float4*)(obase + (size_t)(2 * g + r) * C + 256 * j) = f[r][j];
    }
}

extern "C" void kernel_launch(void* const* d_in, const int* in_sizes, int n_in,
                              void* d_out, int out_size, void* d_ws, size_t ws_size,
                              hipStream_t stream) {
    const float* fea = (const float*)d_in[0];
    const float* emb = (const float*)d_in[1];
    const float* Wq  = (const float*)d_in[2];
    const float* Wk  = (const float*)d_in[3];
    const float* Wv  = (const float*)d_in[4];
    const float* Wp  = (const float*)d_in[5];
    const float* bp  = (const float*)d_in[6];
    float* out = (float*)d_out;

    char* ws = (char*)d_ws;
    float* kbuf = (float*)ws;                                  // B*C f32 = 32KB
    float* vbuf = (float*)(ws + 32 * 1024);                    // 32KB
    __hip_bfloat16* wbuf = (__hip_bfloat16*)(ws + 64 * 1024);  // B*H*C bf16 = 256KB
    __hip_bfloat16* ubuf = (__hip_bfloat16*)(ws + 320 * 1024); // 256KB

    hipLaunchKernelGGL(kv_kernel, dim3(2 * C / 4), dim3(256), 0, stream,
                       emb, Wk, Wv, kbuf, vbuf);
    hipLaunchKernelGGL(wu_kernel, dim3(128), dim3(256), 0, stream,
                       Wq, Wp, kbuf, vbuf, wbuf, ubuf);
    hipLaunchKernelGGL(main_kernel, dim3(N / 64, B), dim3(1024), 0, stream,
                       fea, wbuf, ubuf, bp, out);
}